// Round 4
// baseline (257.429 us; speedup 1.0000x reference)
//
#include <hip/hip_runtime.h>
#include <stdint.h>

#define B_ 2
#define S_ 4096
#define D_ 512
#define H_ 8
#define HD_ 64
#define M_ (B_*S_)   // 8192

typedef __attribute__((ext_vector_type(8))) short bf16x8;
typedef __attribute__((ext_vector_type(4))) float f32x4;

#define QSCALE (0.125f * 1.44269504088896341f)  // 1/sqrt(64) * log2(e)

__device__ __forceinline__ unsigned short f2bf(float f) {
  union { float f; unsigned u; } un; un.f = f;
  unsigned u = un.u;
  return (unsigned short)((u + 0x7fffu + ((u >> 16) & 1u)) >> 16);
}

__device__ __forceinline__ unsigned cvtpk(float lo, float hi) {
  unsigned r;
  asm("v_cvt_pk_bf16_f32 %0, %1, %2" : "=v"(r) : "v"(lo), "v"(hi));
  return r;
}

// async 16B global -> LDS (linear dest: wave-uniform base + lane*16)
__device__ __forceinline__ void gl16(const void* g, void* l) {
  __builtin_amdgcn_global_load_lds(
      (const __attribute__((address_space(1))) void*)g,
      (__attribute__((address_space(3))) void*)l, 16, 0, 0);
}

// K-row permutation: lK row p holds K[kperm_inv(p)]; kperm maps global r -> lds row.
// kperm(r): out bits [r2 r5 r4 r3 r1 r0]; inverse:
__device__ __forceinline__ int kperm_inv(int p) {
  return ((p & 0x1C) << 1) | ((p & 0x20) >> 3) | (p & 3);
}

// ---------------- weight transpose: W[K][N] f32 -> Wt[N][K] bf16 ----------------
__global__ __launch_bounds__(256) void wtrans4(const float* __restrict__ w0, const float* __restrict__ w1,
                                               const float* __restrict__ w2, const float* __restrict__ w3,
                                               unsigned short* __restrict__ t0, unsigned short* __restrict__ t1,
                                               unsigned short* __restrict__ t2, unsigned short* __restrict__ t3) {
  const float* W = blockIdx.z==0?w0: blockIdx.z==1?w1: blockIdx.z==2?w2:w3;
  unsigned short* T = blockIdx.z==0?t0: blockIdx.z==1?t1: blockIdx.z==2?t2:t3;
  __shared__ float tile[32][33];
  int n0 = blockIdx.x*32, k0 = blockIdx.y*32;
  int tx = threadIdx.x & 31, ty = threadIdx.x >> 5;
  #pragma unroll
  for (int i=0;i<4;i++)
    tile[ty + i*8][tx] = W[(size_t)(k0 + ty + i*8)*D_ + n0 + tx];
  __syncthreads();
  #pragma unroll
  for (int i=0;i<4;i++)
    T[(size_t)(n0 + ty + i*8)*D_ + k0 + tx] = f2bf(tile[tx][ty + i*8]);
}

// ---------------- 128x128 bf16 MFMA GEMM, BK=64, 4 waves (2x2), XOR-swizzled LDS ----
// C[m][n] = (sum_k A[m][k] * Wt[n][k] + bias[n]) * oscale
// CONVA: A is f32, convert to bf16 during staging.
// OUT_MODE 0: bf16 head-split [B,H,S,64]; 1: f32 [M,512]; 2: bf16 head-split TRANSPOSED [B,H,64,S]
template<int OUT_MODE, int CONVA>
__device__ __forceinline__ void gemm_body(const void* __restrict__ Ap,
                                          const unsigned short* __restrict__ Wt,
                                          const float* __restrict__ bias,
                                          void* __restrict__ Out, float oscale) {
  __shared__ __align__(16) unsigned short lAB[2*128*64];
  unsigned short* lA = lAB;
  unsigned short* lB = lAB + 128*64;
  int bm = blockIdx.x, bn = blockIdx.y;
  int tid = threadIdx.x, lane = tid & 63, wid = tid >> 6;
  int g = lane >> 4, cc = lane & 15;
  int wm = wid >> 1, wn = wid & 1;

  f32x4 acc[4][4];
  #pragma unroll
  for (int mi=0;mi<4;mi++)
    #pragma unroll
    for (int ni=0;ni<4;ni++)
      acc[mi][ni] = (f32x4){0.f,0.f,0.f,0.f};

  for (int ks = 0; ks < D_; ks += 64) {
    __syncthreads();
    #pragma unroll
    for (int c4 = 0; c4 < 4; c4++) {
      int idx = wid*256 + c4*64 + lane;   // 0..1023 = row*8 + ch
      int row = idx >> 3, ch = idx & 7;
      int sw = ch ^ (row & 7);
      bf16x8 va;
      if (CONVA) {
        const float* a32 = (const float*)Ap + (size_t)(bm*128 + row)*D_ + ks + ch*8;
        float4 f0 = *(const float4*)a32;
        float4 f1 = *(const float4*)(a32 + 4);
        union { unsigned d[4]; bf16x8 v; } u;
        u.d[0] = cvtpk(f0.x, f0.y);
        u.d[1] = cvtpk(f0.z, f0.w);
        u.d[2] = cvtpk(f1.x, f1.y);
        u.d[3] = cvtpk(f1.z, f1.w);
        va = u.v;
      } else {
        va = *(const bf16x8*)((const unsigned short*)Ap + (size_t)(bm*128 + row)*D_ + ks + ch*8);
      }
      bf16x8 vb = *(const bf16x8*)(Wt + (size_t)(bn*128 + row)*D_ + ks + ch*8);
      *(bf16x8*)((char*)lA + row*128 + sw*16) = va;
      *(bf16x8*)((char*)lB + row*128 + sw*16) = vb;
    }
    __syncthreads();
    #pragma unroll
    for (int kk = 0; kk < 2; kk++) {
      bf16x8 af[4], bfv[4];
      #pragma unroll
      for (int mi=0;mi<4;mi++) {
        int row = wm*64 + mi*16 + cc;
        af[mi] = *(const bf16x8*)((const char*)lA + row*128 + (((4*kk+g) ^ (row&7))<<4));
      }
      #pragma unroll
      for (int ni=0;ni<4;ni++) {
        int row = wn*64 + ni*16 + cc;
        bfv[ni] = *(const bf16x8*)((const char*)lB + row*128 + (((4*kk+g) ^ (row&7))<<4));
      }
      #pragma unroll
      for (int mi=0;mi<4;mi++)
        #pragma unroll
        for (int ni=0;ni<4;ni++)
          acc[mi][ni] = __builtin_amdgcn_mfma_f32_16x16x32_bf16(af[mi], bfv[ni], acc[mi][ni], 0, 0, 0);
    }
  }

  if (OUT_MODE == 2) {
    // transpose epilogue: per-wave 64x64 region via LDS bounce -> Out[B,H,HD,S]
    __syncthreads();
    char* ldsT = (char*)lAB + wid*8192;   // 8KB per wave
    #pragma unroll
    for (int ni=0;ni<4;ni++) {
      int n_l = ni*16 + cc;
      float bv = bias[bn*128 + wn*64 + n_l];
      #pragma unroll
      for (int mi=0;mi<4;mi++) {
        ushort4 pk;
        pk.x = f2bf(acc[mi][ni][0] + bv);
        pk.y = f2bf(acc[mi][ni][1] + bv);
        pk.z = f2bf(acc[mi][ni][2] + bv);
        pk.w = f2bf(acc[mi][ni][3] + bv);
        *(ushort4*)(ldsT + n_l*128 + ((32*mi + 8*g) ^ ((n_l&7)<<4))) = pk;
      }
    }
    asm volatile("s_waitcnt lgkmcnt(0)" ::: "memory");
    __builtin_amdgcn_sched_barrier(0);
    #pragma unroll
    for (int it=0; it<8; ++it) {
      int task = it*64 + lane;
      int row = task >> 3, ch = task & 7;   // row = local n (hd), ch*8.. = local m (s)
      bf16x8 vv = *(const bf16x8*)(ldsT + row*128 + ((ch ^ (row&7))<<4));
      int n_g = bn*128 + wn*64 + row;
      int m_g = bm*128 + wm*64 + ch*8;
      int bb = m_g >> 12, ss = m_g & (S_-1);
      int hh = n_g >> 6, hd = n_g & 63;
      *(bf16x8*)((unsigned short*)Out + (((size_t)(bb*H_+hh)*HD_ + hd)*S_ + ss)) = vv;
    }
    return;
  }

  #pragma unroll
  for (int ni=0;ni<4;ni++) {
    int n = bn*128 + wn*64 + ni*16 + cc;
    float bv = bias[n];
    #pragma unroll
    for (int mi=0;mi<4;mi++) {
      f32x4 vacc = acc[mi][ni];
      #pragma unroll
      for (int j=0;j<4;j++) {
        int r = bm*128 + wm*64 + mi*16 + 4*g + j;
        float val = (vacc[j] + bv) * oscale;
        if (OUT_MODE == 0) {
          int b = r >> 12, s = r & (S_-1);
          int h = n >> 6, hd = n & 63;
          ((unsigned short*)Out)[(((size_t)(b*H_ + h)*S_ + s) << 6) + hd] = f2bf(val);
        } else {
          ((float*)Out)[(size_t)r*D_ + n] = val;
        }
      }
    }
  }
}

__global__ __launch_bounds__(256,3) void qk_gemm(
    const float* __restrict__ q32, const float* __restrict__ k32,
    const unsigned short* __restrict__ wqt, const unsigned short* __restrict__ wkt,
    const float* __restrict__ bq, const float* __restrict__ bk,
    unsigned short* __restrict__ Qp, unsigned short* __restrict__ Kp) {
  if (blockIdx.z == 0) gemm_body<0,1>(q32, wqt, bq, Qp, QSCALE);
  else                 gemm_body<0,1>(k32, wkt, bk, Kp, 1.0f);
}

__global__ __launch_bounds__(256,3) void v_gemm(const float* __restrict__ v32,
                                                const unsigned short* __restrict__ wvt,
                                                const float* __restrict__ bv,
                                                unsigned short* __restrict__ Vt) {
  gemm_body<2,1>(v32, wvt, bv, Vt, 1.0f);
}

__global__ __launch_bounds__(256,3) void o_gemm(const unsigned short* __restrict__ att,
                                                const unsigned short* __restrict__ wot,
                                                const float* __restrict__ bo,
                                                float* __restrict__ out) {
  gemm_body<1,0>(att, wot, bo, out, 1.0f);
}

// ---------------- flash attention: QBLK=64 (4 waves x 16 q), KVBLK=64 -------------
// K/V staged by global_load_lds DMA (linear LDS dest; swizzle+perm folded into the
// per-lane global SOURCE address). Raw s_barrier + counted vmcnt keeps the next
// tile's DMA in flight across the whole compute phase. Mask prefetched 1 iter ahead.
__global__ __launch_bounds__(256,4) void fattn(const unsigned short* __restrict__ Qp,
                                               const unsigned short* __restrict__ Kp,
                                               const unsigned short* __restrict__ Vt,
                                               const int* __restrict__ mask,
                                               unsigned short* __restrict__ attO) {
  __shared__ __align__(16) unsigned short lK[2][64*64];
  __shared__ __align__(16) unsigned short lV[2][64*64];
  const int tid = threadIdx.x, lane = tid & 63, wid = tid >> 6;
  const int g = lane >> 4, cc = lane & 15;
  const int bh = blockIdx.y, b = bh >> 3;
  const int q0 = blockIdx.x*64 + wid*16;

  const unsigned short* Qb = Qp + (size_t)bh*S_*HD_;
  const unsigned short* Kb = Kp + (size_t)bh*S_*HD_;
  const unsigned short* Vb = Vt + (size_t)bh*HD_*S_;   // [hd][s]

  // Q as B-fragment: lane holds Q[q0+cc][kk*32 + g*8 ..+7]  (pre-scaled by QSCALE)
  bf16x8 aq[2];
  aq[0] = *(const bf16x8*)(Qb + (size_t)(q0+cc)*HD_ + g*8);
  aq[1] = *(const bf16x8*)(Qb + (size_t)(q0+cc)*HD_ + 32 + g*8);

  // DMA source addresses. Linear LDS dest byte L = wid*1024 + lane*16 (+ 4096*i).
  // L -> (row p = L>>7, slot = (L>>4)&7); K: global row kperm_inv(p), chunk slot^(p&7).
  const int p0 = wid*8 + (lane >> 3);
  const int sl = lane & 7;
  const int cK = sl ^ (p0 & 7);                 // same for p0 and p0+32 (low 3 bits equal)
  const unsigned short* gk0 = Kb + (size_t)kperm_inv(p0)      *HD_ + cK*8;
  const unsigned short* gk1 = Kb + (size_t)kperm_inv(p0 + 32) *HD_ + cK*8;
  const unsigned short* gv0 = Vb + (size_t)p0*S_ + cK*8;      // V: row = hd = p0, same swizzle
  const unsigned short* gv1 = gv0 + (size_t)32*S_;
  const int woff = wid*1024;

  f32x4 o[4];
  #pragma unroll
  for (int t4=0;t4<4;t4++) o[t4] = (f32x4){0.f,0.f,0.f,0.f};
  float mj = 0.f;        // stale running max (log2 domain); scores O(1) so 0 is safe
  float lj = 0.f;        // per-lane PARTIAL row-sum (cross-lane reduce in epilogue)
  const int* mrow = mask + ((size_t)b*S_ + q0 + cc)*S_ + 8*g;

  const int NT = S_/64;

  // prologue: DMA tile 0 into buf 0, prefetch mask tile 0
  {
    char* kb = (char*)lK + woff;
    char* vb = (char*)lV + woff;
    gl16(gk0, kb);
    gl16(gk1, kb + 4096);
    gl16(gv0, vb);
    gl16(gv1, vb + 4096);
  }
  int4 mk0 = *(const int4*)(mrow);
  int4 mk2 = *(const int4*)(mrow + 4);
  int4 mk1 = *(const int4*)(mrow + 32);
  int4 mk3 = *(const int4*)(mrow + 36);

  for (int t = 0; t < NT; ++t) {
    const int cur = t & 1;
    asm volatile("s_waitcnt vmcnt(4)" ::: "memory");   // my 4 DMA for buf[cur] done
    __builtin_amdgcn_s_barrier();                      // all waves' DMA done

    if (t+1 < NT) {   // DMA next tile into buf[cur^1]; stays in flight across compute
      char* kb = (char*)lK + (cur^1)*8192 + woff;
      char* vb = (char*)lV + (cur^1)*8192 + woff;
      gl16(gk0 + (size_t)(t+1)*64*HD_, kb);
      gl16(gk1 + (size_t)(t+1)*64*HD_, kb + 4096);
      gl16(gv0 + (t+1)*64, vb);
      gl16(gv1 + (t+1)*64, vb + 4096);
    }
    // prefetch next tile's mask into registers
    const int tn = (t+1 < NT) ? t+1 : t;
    const int* mr = mrow + (size_t)tn*64;
    int4 nk0 = *(const int4*)(mr);
    int4 nk2 = *(const int4*)(mr + 4);
    int4 nk1 = *(const int4*)(mr + 32);
    int4 nk3 = *(const int4*)(mr + 36);

    const char* bK = (const char*)lK[cur];
    const char* bV = (const char*)lV[cur];

    // QK^T (swapped): st[t4] lane holds S[kv][q=cc], kv = (t4&1)*32 + 8g + (t4>>1)*4 + j
    f32x4 st[4];
    __builtin_amdgcn_s_setprio(1);
    #pragma unroll
    for (int t4=0;t4<4;t4++) {
      int row = t4*16 + cc;
      bf16x8 ak0 = *(const bf16x8*)(bK + row*128 + ((g ^ (row&7)) << 4));
      bf16x8 ak1 = *(const bf16x8*)(bK + row*128 + (((4+g) ^ (row&7)) << 4));
      f32x4 s = (f32x4){0.f,0.f,0.f,0.f};
      s = __builtin_amdgcn_mfma_f32_16x16x32_bf16(ak0, aq[0], s, 0, 0, 0);
      s = __builtin_amdgcn_mfma_f32_16x16x32_bf16(ak1, aq[1], s, 0, 0, 0);
      st[t4] = s;
    }
    __builtin_amdgcn_s_setprio(0);

    // P = exp2(st - mj_stale); zero masked; per-lane partial sum; pack bf16
    float rsum = 0.f;
    unsigned pk32[4][2];
    {
      const int4 mks0 = mk0, mks1 = mk1, mks2 = mk2, mks3 = mk3;
      float e;
      #define SM1(T4, MK)                                             \
        { float e0 = exp2f(st[T4][0] - mj);                           \
          float e1 = exp2f(st[T4][1] - mj);                           \
          float e2 = exp2f(st[T4][2] - mj);                           \
          float e3 = exp2f(st[T4][3] - mj);                           \
          e0 = MK.x ? 0.f : e0;  e1 = MK.y ? 0.f : e1;                \
          e2 = MK.z ? 0.f : e2;  e3 = MK.w ? 0.f : e3;                \
          rsum += (e0 + e1) + (e2 + e3);                              \
          pk32[T4][0] = cvtpk(e0, e1);  pk32[T4][1] = cvtpk(e2, e3); }
      SM1(0, mks0) SM1(1, mks1) SM1(2, mks2) SM1(3, mks3)
      #undef SM1
      (void)e;
    }
    lj += rsum;

    // PV: O[q][hd] += P @ V ; P A-frag is a pure register concat
    __builtin_amdgcn_s_setprio(1);
    #pragma unroll
    for (int kk=0;kk<2;kk++) {
      union { unsigned d[4]; bf16x8 v; } pf;
      pf.d[0] = pk32[kk][0];
      pf.d[1] = pk32[kk][1];
      pf.d[2] = pk32[kk+2][0];
      pf.d[3] = pk32[kk+2][1];
      #pragma unroll
      for (int t4=0;t4<4;t4++) {
        int row = t4*16 + cc;
        bf16x8 bv8 = *(const bf16x8*)(bV + row*128 + (((4*kk+g) ^ (row&7)) << 4));
        o[t4] = __builtin_amdgcn_mfma_f32_16x16x32_bf16(pf.v, bv8, o[t4], 0, 0, 0);
      }
    }
    __builtin_amdgcn_s_setprio(0);

    // max tracking off the critical path; cross-lane work only inside rare branch
    float pm = fmaxf(fmaxf(fmaxf(st[0][0], st[0][1]), fmaxf(st[0][2], st[0][3])),
               fmaxf(fmaxf(fmaxf(st[1][0], st[1][1]), fmaxf(st[1][2], st[1][3])),
               fmaxf(fmaxf(fmaxf(st[2][0], st[2][1]), fmaxf(st[2][2], st[2][3])),
                     fmaxf(fmaxf(st[3][0], st[3][1]), fmaxf(st[3][2], st[3][3])))));
    if (__any(pm > mj + 7.f)) {        // defer-max: rescale only on real growth
      pm = fmaxf(pm, __shfl_xor(pm, 16));
      pm = fmaxf(pm, __shfl_xor(pm, 32));
      float mn = fmaxf(mj, pm);
      float alpha = exp2f(mj - mn);
      mj = mn;
      lj *= alpha;
      #pragma unroll
      for (int j=0;j<4;j++) {
        float aj = __shfl(alpha, 4*g + j);
        #pragma unroll
        for (int t4=0;t4<4;t4++) o[t4][j] *= aj;
      }
    }

    mk0 = nk0; mk1 = nk1; mk2 = nk2; mk3 = nk3;
  }

  // epilogue: reduce lj partials across g, O /= l, store bf16 to att [B,S,D]
  lj += __shfl_xor(lj, 16);
  lj += __shfl_xor(lj, 32);
  const int h = bh & (H_-1);
  float inv = 1.0f / lj;
  #pragma unroll
  for (int j=0;j<4;j++) {
    float ij = __shfl(inv, 4*g + j);
    int qr = q0 + 4*g + j;
    unsigned short* orow = attO + ((size_t)b*S_ + qr)*D_ + h*HD_;
    #pragma unroll
    for (int t4=0;t4<4;t4++)
      orow[t4*16 + cc] = f2bf(o[t4][j] * ij);
  }
}

extern "C" void kernel_launch(void* const* d_in, const int* in_sizes, int n_in,
                              void* d_out, int out_size, void* d_ws, size_t ws_size,
                              hipStream_t stream) {
  const float* q    = (const float*)d_in[0];
  const float* k    = (const float*)d_in[1];
  const float* v    = (const float*)d_in[2];
  const int*   mask = (const int*)  d_in[3];
  const float* wq   = (const float*)d_in[4];
  const float* bq   = (const float*)d_in[5];
  const float* wk   = (const float*)d_in[6];
  const float* bk   = (const float*)d_in[7];
  const float* wv   = (const float*)d_in[8];
  const float* bv   = (const float*)d_in[9];
  const float* wo   = (const float*)d_in[10];
  const float* bo   = (const float*)d_in[11];

  char* ws = (char*)d_ws;
  const size_t SZ_MAT = (size_t)M_ * D_ * 2;   // 8 MiB bf16 [8192,512]
  const size_t SZ_W   = (size_t)D_ * D_ * 2;   // 512 KiB
  unsigned short* wqt = (unsigned short*)(ws);
  unsigned short* wkt = (unsigned short*)(ws + SZ_W);
  unsigned short* wvt = (unsigned short*)(ws + 2*SZ_W);
  unsigned short* wot = (unsigned short*)(ws + 3*SZ_W);
  unsigned short* Qp  = (unsigned short*)(ws + 4*SZ_W);
  unsigned short* Kp  = (unsigned short*)(ws + 4*SZ_W + SZ_MAT);
  unsigned short* Vt  = (unsigned short*)(ws + 4*SZ_W + 2*SZ_MAT);
  unsigned short* att = (unsigned short*)(ws + 4*SZ_W + 3*SZ_MAT);

  wtrans4<<<dim3(16,16,4), 256, 0, stream>>>(wq, wk, wv, wo, wqt, wkt, wvt, wot);
  qk_gemm<<<dim3(64,4,2), 256, 0, stream>>>(q, k, wqt, wkt, bq, bk, Qp, Kp);
  v_gemm<<<dim3(64,4), 256, 0, stream>>>(v, wvt, bv, Vt);
  fattn<<<dim3(64,16), 256, 0, stream>>>(Qp, Kp, Vt, mask, att);
  o_gemm<<<dim3(64,4), 256, 0, stream>>>(att, wot, bo, (float*)d_out);
}

// Round 5
// 224.068 us; speedup vs baseline: 1.1489x; 1.1489x over previous
//
#include <hip/hip_runtime.h>
#include <stdint.h>

#define B_ 2
#define S_ 4096
#define D_ 512
#define H_ 8
#define HD_ 64
#define M_ (B_*S_)   // 8192

typedef __attribute__((ext_vector_type(8))) short bf16x8;
typedef __attribute__((ext_vector_type(4))) float f32x4;

#define QSCALE (0.125f * 1.44269504088896341f)  // 1/sqrt(64) * log2(e)

__device__ __forceinline__ unsigned short f2bf(float f) {
  union { float f; unsigned u; } un; un.f = f;
  unsigned u = un.u;
  return (unsigned short)((u + 0x7fffu + ((u >> 16) & 1u)) >> 16);
}

__device__ __forceinline__ unsigned cvtpk(float lo, float hi) {
  unsigned r;
  asm("v_cvt_pk_bf16_f32 %0, %1, %2" : "=v"(r) : "v"(lo), "v"(hi));
  return r;
}

// async 16B global -> LDS (linear dest: wave-uniform base + lane*16)
__device__ __forceinline__ void gl16(const void* g, void* l) {
  __builtin_amdgcn_global_load_lds(
      (const __attribute__((address_space(1))) void*)g,
      (__attribute__((address_space(3))) void*)l, 16, 0, 0);
}

// K-row permutation: lK row p holds K[kperm_inv(p)].
__device__ __forceinline__ int kperm_inv(int p) {
  return ((p & 0x1C) << 1) | ((p & 0x20) >> 3) | (p & 3);
}

// ---------------- weight transpose: W[K][N] f32 -> Wt[N][K] bf16 ----------------
__global__ __launch_bounds__(256) void wtrans4(const float* __restrict__ w0, const float* __restrict__ w1,
                                               const float* __restrict__ w2, const float* __restrict__ w3,
                                               unsigned short* __restrict__ t0, unsigned short* __restrict__ t1,
                                               unsigned short* __restrict__ t2, unsigned short* __restrict__ t3) {
  const float* W = blockIdx.z==0?w0: blockIdx.z==1?w1: blockIdx.z==2?w2:w3;
  unsigned short* T = blockIdx.z==0?t0: blockIdx.z==1?t1: blockIdx.z==2?t2:t3;
  __shared__ float tile[32][33];
  int n0 = blockIdx.x*32, k0 = blockIdx.y*32;
  int tx = threadIdx.x & 31, ty = threadIdx.x >> 5;
  #pragma unroll
  for (int i=0;i<4;i++)
    tile[ty + i*8][tx] = W[(size_t)(k0 + ty + i*8)*D_ + n0 + tx];
  __syncthreads();
  #pragma unroll
  for (int i=0;i<4;i++)
    T[(size_t)(n0 + ty + i*8)*D_ + k0 + tx] = f2bf(tile[tx][ty + i*8]);
}

// ---------------- 128x128 bf16 MFMA GEMM, BK=64, 4 waves (2x2), XOR-swizzled LDS ----
template<int OUT_MODE, int CONVA>
__device__ __forceinline__ void gemm_body(const void* __restrict__ Ap,
                                          const unsigned short* __restrict__ Wt,
                                          const float* __restrict__ bias,
                                          void* __restrict__ Out, float oscale) {
  __shared__ __align__(16) unsigned short lAB[2*128*64];
  unsigned short* lA = lAB;
  unsigned short* lB = lAB + 128*64;
  int bm = blockIdx.x, bn = blockIdx.y;
  int tid = threadIdx.x, lane = tid & 63, wid = tid >> 6;
  int g = lane >> 4, cc = lane & 15;
  int wm = wid >> 1, wn = wid & 1;

  f32x4 acc[4][4];
  #pragma unroll
  for (int mi=0;mi<4;mi++)
    #pragma unroll
    for (int ni=0;ni<4;ni++)
      acc[mi][ni] = (f32x4){0.f,0.f,0.f,0.f};

  for (int ks = 0; ks < D_; ks += 64) {
    __syncthreads();
    #pragma unroll
    for (int c4 = 0; c4 < 4; c4++) {
      int idx = wid*256 + c4*64 + lane;   // 0..1023 = row*8 + ch
      int row = idx >> 3, ch = idx & 7;
      int sw = ch ^ (row & 7);
      bf16x8 va;
      if (CONVA) {
        const float* a32 = (const float*)Ap + (size_t)(bm*128 + row)*D_ + ks + ch*8;
        float4 f0 = *(const float4*)a32;
        float4 f1 = *(const float4*)(a32 + 4);
        union { unsigned d[4]; bf16x8 v; } u;
        u.d[0] = cvtpk(f0.x, f0.y);
        u.d[1] = cvtpk(f0.z, f0.w);
        u.d[2] = cvtpk(f1.x, f1.y);
        u.d[3] = cvtpk(f1.z, f1.w);
        va = u.v;
      } else {
        va = *(const bf16x8*)((const unsigned short*)Ap + (size_t)(bm*128 + row)*D_ + ks + ch*8);
      }
      bf16x8 vb = *(const bf16x8*)(Wt + (size_t)(bn*128 + row)*D_ + ks + ch*8);
      *(bf16x8*)((char*)lA + row*128 + sw*16) = va;
      *(bf16x8*)((char*)lB + row*128 + sw*16) = vb;
    }
    __syncthreads();
    #pragma unroll
    for (int kk = 0; kk < 2; kk++) {
      bf16x8 af[4], bfv[4];
      #pragma unroll
      for (int mi=0;mi<4;mi++) {
        int row = wm*64 + mi*16 + cc;
        af[mi] = *(const bf16x8*)((const char*)lA + row*128 + (((4*kk+g) ^ (row&7))<<4));
      }
      #pragma unroll
      for (int ni=0;ni<4;ni++) {
        int row = wn*64 + ni*16 + cc;
        bfv[ni] = *(const bf16x8*)((const char*)lB + row*128 + (((4*kk+g) ^ (row&7))<<4));
      }
      #pragma unroll
      for (int mi=0;mi<4;mi++)
        #pragma unroll
        for (int ni=0;ni<4;ni++)
          acc[mi][ni] = __builtin_amdgcn_mfma_f32_16x16x32_bf16(af[mi], bfv[ni], acc[mi][ni], 0, 0, 0);
    }
  }

  if (OUT_MODE == 2) {
    // transpose epilogue: per-wave 64x64 region via LDS bounce -> Out[B,H,HD,S]
    __syncthreads();
    char* ldsT = (char*)lAB + wid*8192;   // 8KB per wave
    #pragma unroll
    for (int ni=0;ni<4;ni++) {
      int n_l = ni*16 + cc;
      float bv = bias[bn*128 + wn*64 + n_l];
      #pragma unroll
      for (int mi=0;mi<4;mi++) {
        ushort4 pk;
        pk.x = f2bf(acc[mi][ni][0] + bv);
        pk.y = f2bf(acc[mi][ni][1] + bv);
        pk.z = f2bf(acc[mi][ni][2] + bv);
        pk.w = f2bf(acc[mi][ni][3] + bv);
        *(ushort4*)(ldsT + n_l*128 + ((32*mi + 8*g) ^ ((n_l&7)<<4))) = pk;
      }
    }
    asm volatile("s_waitcnt lgkmcnt(0)" ::: "memory");
    __builtin_amdgcn_sched_barrier(0);
    #pragma unroll
    for (int it=0; it<8; ++it) {
      int task = it*64 + lane;
      int row = task >> 3, ch = task & 7;
      bf16x8 vv = *(const bf16x8*)(ldsT + row*128 + ((ch ^ (row&7))<<4));
      int n_g = bn*128 + wn*64 + row;
      int m_g = bm*128 + wm*64 + ch*8;
      int bb = m_g >> 12, ss = m_g & (S_-1);
      int hh = n_g >> 6, hd = n_g & 63;
      *(bf16x8*)((unsigned short*)Out + (((size_t)(bb*H_+hh)*HD_ + hd)*S_ + ss)) = vv;
    }
    return;
  }

  #pragma unroll
  for (int ni=0;ni<4;ni++) {
    int n = bn*128 + wn*64 + ni*16 + cc;
    float bv = bias[n];
    #pragma unroll
    for (int mi=0;mi<4;mi++) {
      f32x4 vacc = acc[mi][ni];
      #pragma unroll
      for (int j=0;j<4;j++) {
        int r = bm*128 + wm*64 + mi*16 + 4*g + j;
        float val = (vacc[j] + bv) * oscale;
        if (OUT_MODE == 0) {
          int b = r >> 12, s = r & (S_-1);
          int h = n >> 6, hd = n & 63;
          ((unsigned short*)Out)[(((size_t)(b*H_ + h)*S_ + s) << 6) + hd] = f2bf(val);
        } else {
          ((float*)Out)[(size_t)r*D_ + n] = val;
        }
      }
    }
  }
}

__global__ __launch_bounds__(256,3) void qkv_gemm(
    const float* __restrict__ q32, const float* __restrict__ k32, const float* __restrict__ v32,
    const unsigned short* __restrict__ wqt, const unsigned short* __restrict__ wkt,
    const unsigned short* __restrict__ wvt,
    const float* __restrict__ bq, const float* __restrict__ bk, const float* __restrict__ bv,
    unsigned short* __restrict__ Qp, unsigned short* __restrict__ Kp,
    unsigned short* __restrict__ Vt) {
  if (blockIdx.z == 0)      gemm_body<0,1>(q32, wqt, bq, Qp, QSCALE);
  else if (blockIdx.z == 1) gemm_body<0,1>(k32, wkt, bk, Kp, 1.0f);
  else                      gemm_body<2,1>(v32, wvt, bv, Vt, 1.0f);
}

__global__ __launch_bounds__(256,3) void o_gemm(const unsigned short* __restrict__ att,
                                                const unsigned short* __restrict__ wot,
                                                const float* __restrict__ bo,
                                                float* __restrict__ out) {
  gemm_body<1,0>(att, wot, bo, out, 1.0f);
}

// ---------------- flash attention: QBLK=64 (4 waves x 16 q), KVBLK=64 -------------
// kv loop unrolled x2 (compile-time buffer offsets -> loop-invariant LDS addrs).
// DMA staging + mask prefetch issued at top of tile; single vmcnt(0)+s_barrier.
// Row-sums accumulated via ones-MFMA directly in o-fragment layout.

#define FA_ISSUE(NCUR, MN)                                              \
    { char* kb = lds + (NCUR)*8192 + woff;                              \
      gl16(gkA, kb); gl16(gkB, kb + 4096);                              \
      gl16(gvA, kb + 16384); gl16(gvB, kb + 16384 + 4096);              \
      gkA += 64*HD_; gkB += 64*HD_; gvA += 64; gvB += 64;               \
      MN##0 = *(const int4*)(mrow);                                     \
      MN##2 = *(const int4*)(mrow + 4);                                 \
      MN##1 = *(const int4*)(mrow + 32);                                \
      MN##3 = *(const int4*)(mrow + 36);                                \
      mrow += 64; }

#define FA_TILE(CUR, MC, DOISSUE, NM)                                       \
  { asm volatile("s_waitcnt vmcnt(0)" ::: "memory");                        \
    __builtin_amdgcn_s_barrier();                                           \
    if (DOISSUE) FA_ISSUE((CUR)^1, NM)                                      \
    f32x4 st[4];                                                            \
    __builtin_amdgcn_s_setprio(1);                                          \
    _Pragma("unroll")                                                       \
    for (int t4=0;t4<4;t4++) {                                              \
      bf16x8 ak0 = *(const bf16x8*)(lds + (CUR)*8192 + rdO[t4][0]);         \
      bf16x8 ak1 = *(const bf16x8*)(lds + (CUR)*8192 + rdO[t4][1]);         \
      f32x4 s = (f32x4){0.f,0.f,0.f,0.f};                                   \
      s = __builtin_amdgcn_mfma_f32_16x16x32_bf16(ak0, aq[0], s, 0,0,0);    \
      s = __builtin_amdgcn_mfma_f32_16x16x32_bf16(ak1, aq[1], s, 0,0,0);    \
      st[t4] = s;                                                           \
    }                                                                       \
    __builtin_amdgcn_s_setprio(0);                                          \
    union { unsigned d[2][4]; bf16x8 v[2]; } P;                             \
    _Pragma("unroll")                                                       \
    for (int t4=0;t4<4;t4++) {                                              \
      float e0 = __builtin_amdgcn_exp2f(st[t4][0] - mj);                    \
      float e1 = __builtin_amdgcn_exp2f(st[t4][1] - mj);                    \
      float e2 = __builtin_amdgcn_exp2f(st[t4][2] - mj);                    \
      float e3 = __builtin_amdgcn_exp2f(st[t4][3] - mj);                    \
      const int4 mk = (t4==0)?MC##0:(t4==1)?MC##1:(t4==2)?MC##2:MC##3;      \
      e0 = mk.x ? 0.f : e0;  e1 = mk.y ? 0.f : e1;                          \
      e2 = mk.z ? 0.f : e2;  e3 = mk.w ? 0.f : e3;                          \
      P.d[t4&1][(t4>>1)*2]   = cvtpk(e0, e1);                               \
      P.d[t4&1][(t4>>1)*2+1] = cvtpk(e2, e3);                               \
    }                                                                       \
    __builtin_amdgcn_s_setprio(1);                                          \
    _Pragma("unroll")                                                       \
    for (int kk=0;kk<2;kk++) {                                              \
      lj4 = __builtin_amdgcn_mfma_f32_16x16x32_bf16(P.v[kk], vones, lj4, 0,0,0); \
      _Pragma("unroll")                                                     \
      for (int t4=0;t4<4;t4++) {                                            \
        bf16x8 bv8 = *(const bf16x8*)(lds + 16384 + (CUR)*8192 + rdO[t4][kk]); \
        o[t4] = __builtin_amdgcn_mfma_f32_16x16x32_bf16(P.v[kk], bv8, o[t4], 0,0,0); \
      }                                                                     \
    }                                                                       \
    __builtin_amdgcn_s_setprio(0);                                          \
    float pm = fmaxf(fmaxf(fmaxf(st[0][0],st[0][1]),fmaxf(st[0][2],st[0][3])),   \
               fmaxf(fmaxf(fmaxf(st[1][0],st[1][1]),fmaxf(st[1][2],st[1][3])),   \
               fmaxf(fmaxf(fmaxf(st[2][0],st[2][1]),fmaxf(st[2][2],st[2][3])),   \
                     fmaxf(fmaxf(st[3][0],st[3][1]),fmaxf(st[3][2],st[3][3]))))); \
    if (__any(pm > mj + 7.f)) {                                             \
      pm = fmaxf(pm, __shfl_xor(pm, 16));                                   \
      pm = fmaxf(pm, __shfl_xor(pm, 32));                                   \
      float mn = fmaxf(mj, pm);                                             \
      float alpha = __builtin_amdgcn_exp2f(mj - mn);                        \
      mj = mn;                                                              \
      _Pragma("unroll")                                                     \
      for (int j=0;j<4;j++) {                                               \
        float aj = __shfl(alpha, 4*g + j);                                  \
        lj4[j] *= aj;                                                       \
        _Pragma("unroll")                                                   \
        for (int t4=0;t4<4;t4++) o[t4][j] *= aj;                            \
      }                                                                     \
    } }

__global__ __launch_bounds__(256,4) void fattn(const unsigned short* __restrict__ Qp,
                                               const unsigned short* __restrict__ Kp,
                                               const unsigned short* __restrict__ Vt,
                                               const int* __restrict__ mask,
                                               unsigned short* __restrict__ attO) {
  // layout: [K buf0 8K][K buf1 8K][V buf0 8K][V buf1 8K]
  __shared__ __align__(16) char lds[32768];
  const int tid = threadIdx.x, lane = tid & 63, wid = tid >> 6;
  const int g = lane >> 4, cc = lane & 15;
  const int bh = blockIdx.y, b = bh >> 3;
  const int q0 = blockIdx.x*64 + wid*16;

  const unsigned short* Qb = Qp + (size_t)bh*S_*HD_;
  const unsigned short* Kb = Kp + (size_t)bh*S_*HD_;
  const unsigned short* Vb = Vt + (size_t)bh*HD_*S_;   // [hd][s]

  // Q as B-fragment (pre-scaled by QSCALE)
  bf16x8 aq[2];
  aq[0] = *(const bf16x8*)(Qb + (size_t)(q0+cc)*HD_ + g*8);
  aq[1] = *(const bf16x8*)(Qb + (size_t)(q0+cc)*HD_ + 32 + g*8);

  // loop-invariant swizzled LDS read offsets (same for K reads and PV reads)
  int rdO[4][2];
  #pragma unroll
  for (int t4=0;t4<4;t4++) {
    int row = t4*16 + cc;
    int base = row*128 + ((g ^ (row&7)) << 4);
    rdO[t4][0] = base;
    rdO[t4][1] = base ^ 64;
  }

  // DMA source addresses (swizzle+perm folded into per-lane global source)
  const int p0 = wid*8 + (lane >> 3);
  const int sl = lane & 7;
  const int cK = sl ^ (p0 & 7);
  const unsigned short* gkA = Kb + (size_t)kperm_inv(p0)      *HD_ + cK*8;
  const unsigned short* gkB = Kb + (size_t)kperm_inv(p0 + 32) *HD_ + cK*8;
  const unsigned short* gvA = Vb + (size_t)p0*S_ + cK*8;
  const unsigned short* gvB = gvA + (size_t)32*S_;
  const int woff = wid*1024;

  union { unsigned d[4]; bf16x8 v; } onesu;
  onesu.d[0] = onesu.d[1] = onesu.d[2] = onesu.d[3] = 0x3F803F80u;
  const bf16x8 vones = onesu.v;

  f32x4 o[4];
  #pragma unroll
  for (int t4=0;t4<4;t4++) o[t4] = (f32x4){0.f,0.f,0.f,0.f};
  f32x4 lj4 = (f32x4){0.f,0.f,0.f,0.f};
  float mj = 0.f;     // stale running max (log2 domain); scores O(1) so 0 is safe
  const int* mrow = mask + ((size_t)b*S_ + q0 + cc)*S_ + 8*g;

  int4 ma0={0,0,0,0}, ma1={0,0,0,0}, ma2={0,0,0,0}, ma3={0,0,0,0};
  int4 mb0={0,0,0,0}, mb1={0,0,0,0}, mb2={0,0,0,0}, mb3={0,0,0,0};

  const int NT = S_/64;   // 64

  // prologue: stage tile 0 into buf0, mask(0) into ma
  FA_ISSUE(0, ma)

  #pragma unroll 1
  for (int t2 = 0; t2 < NT; t2 += 2) {
    FA_TILE(0, ma, true,         mb)
    FA_TILE(1, mb, (t2+2 < NT),  ma)
  }

  // epilogue: inv from lj4 directly (already in o-fragment layout)
  const int h = bh & (H_-1);
  #pragma unroll
  for (int j=0;j<4;j++) {
    float ij = __builtin_amdgcn_rcpf(lj4[j]);
    int qr = q0 + 4*g + j;
    unsigned short* orow = attO + ((size_t)b*S_ + qr)*D_ + h*HD_;
    #pragma unroll
    for (int t4=0;t4<4;t4++)
      orow[t4*16 + cc] = f2bf(o[t4][j] * ij);
  }
}

extern "C" void kernel_launch(void* const* d_in, const int* in_sizes, int n_in,
                              void* d_out, int out_size, void* d_ws, size_t ws_size,
                              hipStream_t stream) {
  const float* q    = (const float*)d_in[0];
  const float* k    = (const float*)d_in[1];
  const float* v    = (const float*)d_in[2];
  const int*   mask = (const int*)  d_in[3];
  const float* wq   = (const float*)d_in[4];
  const float* bq   = (const float*)d_in[5];
  const float* wk   = (const float*)d_in[6];
  const float* bk   = (const float*)d_in[7];
  const float* wv   = (const float*)d_in[8];
  const float* bv   = (const float*)d_in[9];
  const float* wo   = (const float*)d_in[10];
  const float* bo   = (const float*)d_in[11];

  char* ws = (char*)d_ws;
  const size_t SZ_MAT = (size_t)M_ * D_ * 2;   // 8 MiB bf16 [8192,512]
  const size_t SZ_W   = (size_t)D_ * D_ * 2;   // 512 KiB
  unsigned short* wqt = (unsigned short*)(ws);
  unsigned short* wkt = (unsigned short*)(ws + SZ_W);
  unsigned short* wvt = (unsigned short*)(ws + 2*SZ_W);
  unsigned short* wot = (unsigned short*)(ws + 3*SZ_W);
  unsigned short* Qp  = (unsigned short*)(ws + 4*SZ_W);
  unsigned short* Kp  = (unsigned short*)(ws + 4*SZ_W + SZ_MAT);
  unsigned short* Vt  = (unsigned short*)(ws + 4*SZ_W + 2*SZ_MAT);
  unsigned short* att = (unsigned short*)(ws + 4*SZ_W + 3*SZ_MAT);

  wtrans4<<<dim3(16,16,4), 256, 0, stream>>>(wq, wk, wv, wo, wqt, wkt, wvt, wot);
  qkv_gemm<<<dim3(64,4,3), 256, 0, stream>>>(q, k, v, wqt, wkt, wvt,
                                             bq, bk, bv, Qp, Kp, Vt);
  fattn<<<dim3(64,16), 256, 0, stream>>>(Qp, Kp, Vt, mask, att);
  o_gemm<<<dim3(64,4), 256, 0, stream>>>(att, wot, bo, (float*)d_out);
}

// Round 6
// 202.640 us; speedup vs baseline: 1.2704x; 1.1057x over previous
//
#include <hip/hip_runtime.h>
#include <stdint.h>

#define B_ 2
#define S_ 4096
#define D_ 512
#define H_ 8
#define HD_ 64
#define M_ (B_*S_)   // 8192

typedef __attribute__((ext_vector_type(8))) short bf16x8;
typedef __attribute__((ext_vector_type(4))) float f32x4;

#define QSCALE (0.125f * 1.44269504088896341f)  // 1/sqrt(64) * log2(e)

__device__ __forceinline__ unsigned short f2bf(float f) {
  union { float f; unsigned u; } un; un.f = f;
  unsigned u = un.u;
  return (unsigned short)((u + 0x7fffu + ((u >> 16) & 1u)) >> 16);
}

__device__ __forceinline__ unsigned cvtpk(float lo, float hi) {
  unsigned r;
  asm("v_cvt_pk_bf16_f32 %0, %1, %2" : "=v"(r) : "v"(lo), "v"(hi));
  return r;
}

// async 16B global -> LDS (linear dest: wave-uniform base + lane*16)
__device__ __forceinline__ void gl16(const void* g, void* l) {
  __builtin_amdgcn_global_load_lds(
      (const __attribute__((address_space(1))) void*)g,
      (__attribute__((address_space(3))) void*)l, 16, 0, 0);
}

// K-row permutation: lK row p holds K[kperm_inv(p)].
__device__ __forceinline__ int kperm_inv(int p) {
  return ((p & 0x1C) << 1) | ((p & 0x20) >> 3) | (p & 3);
}

// ---------------- mask bit-pack: int32 [2,S,S] -> 1 bit per elem -------------
// word w covers mask[w*64 .. w*64+63]; bit i = (mask[w*64+i] != 0)
__global__ __launch_bounds__(256) void mpack(const int* __restrict__ mask,
                                             unsigned long long* __restrict__ bits) {
  const int nw = (gridDim.x * 256) >> 6;
  int w = (blockIdx.x * 256 + threadIdx.x) >> 6;
  int lane = threadIdx.x & 63;
  const int NWORD = (int)((size_t)B_ * S_ * S_ / 64);
  for (int word = w; word < NWORD; word += nw) {
    int m = mask[(size_t)word * 64 + lane];
    unsigned long long bal = __ballot(m != 0);
    if (lane == 0) bits[word] = bal;
  }
}

// ---------------- weight transpose: W[K][N] f32 -> Wt[N][K] bf16 ----------------
__global__ __launch_bounds__(256) void wtrans4(const float* __restrict__ w0, const float* __restrict__ w1,
                                               const float* __restrict__ w2, const float* __restrict__ w3,
                                               unsigned short* __restrict__ t0, unsigned short* __restrict__ t1,
                                               unsigned short* __restrict__ t2, unsigned short* __restrict__ t3) {
  const float* W = blockIdx.z==0?w0: blockIdx.z==1?w1: blockIdx.z==2?w2:w3;
  unsigned short* T = blockIdx.z==0?t0: blockIdx.z==1?t1: blockIdx.z==2?t2:t3;
  __shared__ float tile[32][33];
  int n0 = blockIdx.x*32, k0 = blockIdx.y*32;
  int tx = threadIdx.x & 31, ty = threadIdx.x >> 5;
  #pragma unroll
  for (int i=0;i<4;i++)
    tile[ty + i*8][tx] = W[(size_t)(k0 + ty + i*8)*D_ + n0 + tx];
  __syncthreads();
  #pragma unroll
  for (int i=0;i<4;i++)
    T[(size_t)(n0 + ty + i*8)*D_ + k0 + tx] = f2bf(tile[tx][ty + i*8]);
}

// ---------------- 128x128 bf16 MFMA GEMM, BK=64, 4 waves (2x2), XOR-swizzled LDS ----
template<int OUT_MODE, int CONVA>
__device__ __forceinline__ void gemm_body(const void* __restrict__ Ap,
                                          const unsigned short* __restrict__ Wt,
                                          const float* __restrict__ bias,
                                          void* __restrict__ Out, float oscale) {
  __shared__ __align__(16) unsigned short lAB[2*128*64];
  unsigned short* lA = lAB;
  unsigned short* lB = lAB + 128*64;
  int bm = blockIdx.x, bn = blockIdx.y;
  int tid = threadIdx.x, lane = tid & 63, wid = tid >> 6;
  int g = lane >> 4, cc = lane & 15;
  int wm = wid >> 1, wn = wid & 1;

  f32x4 acc[4][4];
  #pragma unroll
  for (int mi=0;mi<4;mi++)
    #pragma unroll
    for (int ni=0;ni<4;ni++)
      acc[mi][ni] = (f32x4){0.f,0.f,0.f,0.f};

  for (int ks = 0; ks < D_; ks += 64) {
    __syncthreads();
    #pragma unroll
    for (int c4 = 0; c4 < 4; c4++) {
      int idx = wid*256 + c4*64 + lane;   // 0..1023 = row*8 + ch
      int row = idx >> 3, ch = idx & 7;
      int sw = ch ^ (row & 7);
      bf16x8 va;
      if (CONVA) {
        const float* a32 = (const float*)Ap + (size_t)(bm*128 + row)*D_ + ks + ch*8;
        float4 f0 = *(const float4*)a32;
        float4 f1 = *(const float4*)(a32 + 4);
        union { unsigned d[4]; bf16x8 v; } u;
        u.d[0] = cvtpk(f0.x, f0.y);
        u.d[1] = cvtpk(f0.z, f0.w);
        u.d[2] = cvtpk(f1.x, f1.y);
        u.d[3] = cvtpk(f1.z, f1.w);
        va = u.v;
      } else {
        va = *(const bf16x8*)((const unsigned short*)Ap + (size_t)(bm*128 + row)*D_ + ks + ch*8);
      }
      bf16x8 vb = *(const bf16x8*)(Wt + (size_t)(bn*128 + row)*D_ + ks + ch*8);
      *(bf16x8*)((char*)lA + row*128 + sw*16) = va;
      *(bf16x8*)((char*)lB + row*128 + sw*16) = vb;
    }
    __syncthreads();
    #pragma unroll
    for (int kk = 0; kk < 2; kk++) {
      bf16x8 af[4], bfv[4];
      #pragma unroll
      for (int mi=0;mi<4;mi++) {
        int row = wm*64 + mi*16 + cc;
        af[mi] = *(const bf16x8*)((const char*)lA + row*128 + (((4*kk+g) ^ (row&7))<<4));
      }
      #pragma unroll
      for (int ni=0;ni<4;ni++) {
        int row = wn*64 + ni*16 + cc;
        bfv[ni] = *(const bf16x8*)((const char*)lB + row*128 + (((4*kk+g) ^ (row&7))<<4));
      }
      #pragma unroll
      for (int mi=0;mi<4;mi++)
        #pragma unroll
        for (int ni=0;ni<4;ni++)
          acc[mi][ni] = __builtin_amdgcn_mfma_f32_16x16x32_bf16(af[mi], bfv[ni], acc[mi][ni], 0, 0, 0);
    }
  }

  if (OUT_MODE == 2) {
    // transpose epilogue: per-wave 64x64 region via LDS bounce -> Out[B,H,HD,S]
    __syncthreads();
    char* ldsT = (char*)lAB + wid*8192;   // 8KB per wave
    #pragma unroll
    for (int ni=0;ni<4;ni++) {
      int n_l = ni*16 + cc;
      float bv = bias[bn*128 + wn*64 + n_l];
      #pragma unroll
      for (int mi=0;mi<4;mi++) {
        ushort4 pk;
        pk.x = f2bf(acc[mi][ni][0] + bv);
        pk.y = f2bf(acc[mi][ni][1] + bv);
        pk.z = f2bf(acc[mi][ni][2] + bv);
        pk.w = f2bf(acc[mi][ni][3] + bv);
        *(ushort4*)(ldsT + n_l*128 + ((32*mi + 8*g) ^ ((n_l&7)<<4))) = pk;
      }
    }
    asm volatile("s_waitcnt lgkmcnt(0)" ::: "memory");
    __builtin_amdgcn_sched_barrier(0);
    #pragma unroll
    for (int it=0; it<8; ++it) {
      int task = it*64 + lane;
      int row = task >> 3, ch = task & 7;
      bf16x8 vv = *(const bf16x8*)(ldsT + row*128 + ((ch ^ (row&7))<<4));
      int n_g = bn*128 + wn*64 + row;
      int m_g = bm*128 + wm*64 + ch*8;
      int bb = m_g >> 12, ss = m_g & (S_-1);
      int hh = n_g >> 6, hd = n_g & 63;
      *(bf16x8*)((unsigned short*)Out + (((size_t)(bb*H_+hh)*HD_ + hd)*S_ + ss)) = vv;
    }
    return;
  }

  #pragma unroll
  for (int ni=0;ni<4;ni++) {
    int n = bn*128 + wn*64 + ni*16 + cc;
    float bv = bias[n];
    #pragma unroll
    for (int mi=0;mi<4;mi++) {
      f32x4 vacc = acc[mi][ni];
      #pragma unroll
      for (int j=0;j<4;j++) {
        int r = bm*128 + wm*64 + mi*16 + 4*g + j;
        float val = (vacc[j] + bv) * oscale;
        if (OUT_MODE == 0) {
          int b = r >> 12, s = r & (S_-1);
          int h = n >> 6, hd = n & 63;
          ((unsigned short*)Out)[(((size_t)(b*H_ + h)*S_ + s) << 6) + hd] = f2bf(val);
        } else {
          ((float*)Out)[(size_t)r*D_ + n] = val;
        }
      }
    }
  }
}

__global__ __launch_bounds__(256,3) void qkv_gemm(
    const float* __restrict__ q32, const float* __restrict__ k32, const float* __restrict__ v32,
    const unsigned short* __restrict__ wqt, const unsigned short* __restrict__ wkt,
    const unsigned short* __restrict__ wvt,
    const float* __restrict__ bq, const float* __restrict__ bk, const float* __restrict__ bv,
    unsigned short* __restrict__ Qp, unsigned short* __restrict__ Kp,
    unsigned short* __restrict__ Vt) {
  if (blockIdx.z == 0)      gemm_body<0,1>(q32, wqt, bq, Qp, QSCALE);
  else if (blockIdx.z == 1) gemm_body<0,1>(k32, wkt, bk, Kp, 1.0f);
  else                      gemm_body<2,1>(v32, wvt, bv, Vt, 1.0f);
}

__global__ __launch_bounds__(256,3) void o_gemm(const unsigned short* __restrict__ att,
                                                const unsigned short* __restrict__ wot,
                                                const float* __restrict__ bo,
                                                float* __restrict__ out) {
  gemm_body<1,0>(att, wot, bo, out, 1.0f);
}

// ---------------- flash attention: QBLK=128 (4 waves x 32 q), KVBLK=64 ------------
// Each wave owns 32 q (2 Q B-frags) -> every K/V ds_read feeds 2 MFMAs.
// K/V staged by global_load_lds DMA (swizzle+perm folded into global source addr).
// Mask consumed as pre-packed bits (8B per 64 kv per q-row). Stale-max softmax.

#define FA_ISSUE(NCUR, MN0, MN1)                                        \
    { char* kb = lds + (NCUR)*8192 + woff;                              \
      gl16(gkA, kb); gl16(gkB, kb + 4096);                              \
      gl16(gvA, kb + 16384); gl16(gvB, kb + 16384 + 4096);              \
      gkA += 64*HD_; gkB += 64*HD_; gvA += 64; gvB += 64;               \
      MN0 = *mb0p++; MN1 = *mb1p++; }

#define FA_TILE(CUR, MC0, MC1, DOISSUE, MN0, MN1)                             \
  { asm volatile("s_waitcnt vmcnt(0)" ::: "memory");                          \
    __builtin_amdgcn_s_barrier();                                             \
    if (DOISSUE) FA_ISSUE((CUR)^1, MN0, MN1)                                  \
    f32x4 st0[4], st1[4];                                                     \
    __builtin_amdgcn_s_setprio(1);                                            \
    _Pragma("unroll")                                                         \
    for (int t4=0;t4<4;t4++) {                                                \
      bf16x8 ak0 = *(const bf16x8*)(lds + (CUR)*8192 + rdO[t4][0]);           \
      bf16x8 ak1 = *(const bf16x8*)(lds + (CUR)*8192 + rdO[t4][1]);           \
      f32x4 s0 = (f32x4){0.f,0.f,0.f,0.f};                                    \
      s0 = __builtin_amdgcn_mfma_f32_16x16x32_bf16(ak0, aq00, s0, 0,0,0);     \
      s0 = __builtin_amdgcn_mfma_f32_16x16x32_bf16(ak1, aq01, s0, 0,0,0);     \
      f32x4 s1 = (f32x4){0.f,0.f,0.f,0.f};                                    \
      s1 = __builtin_amdgcn_mfma_f32_16x16x32_bf16(ak0, aq10, s1, 0,0,0);     \
      s1 = __builtin_amdgcn_mfma_f32_16x16x32_bf16(ak1, aq11, s1, 0,0,0);     \
      st0[t4] = s0; st1[t4] = s1;                                             \
    }                                                                         \
    __builtin_amdgcn_s_setprio(0);                                            \
    unsigned long long sh0 = MC0 >> g8, sh1 = MC1 >> g8;                      \
    unsigned lo0 = (unsigned)sh0, hi0 = (unsigned)(sh0 >> 32);                \
    unsigned lo1 = (unsigned)sh1, hi1 = (unsigned)(sh1 >> 32);                \
    union { unsigned d[2][4]; bf16x8 v[2]; } P0, P1;                          \
    _Pragma("unroll")                                                         \
    for (int t4=0;t4<4;t4++) {                                                \
      unsigned bm0 = (t4 & 1) ? hi0 : lo0;                                    \
      unsigned bm1 = (t4 & 1) ? hi1 : lo1;                                    \
      const int bb = (t4 >> 1) * 4;                                           \
      float a0 = __builtin_amdgcn_exp2f(st0[t4][0] - mj);                     \
      float a1 = __builtin_amdgcn_exp2f(st0[t4][1] - mj);                     \
      float a2 = __builtin_amdgcn_exp2f(st0[t4][2] - mj);                     \
      float a3 = __builtin_amdgcn_exp2f(st0[t4][3] - mj);                     \
      a0 = (bm0 & (1u<<(bb+0))) ? 0.f : a0;                                   \
      a1 = (bm0 & (1u<<(bb+1))) ? 0.f : a1;                                   \
      a2 = (bm0 & (1u<<(bb+2))) ? 0.f : a2;                                   \
      a3 = (bm0 & (1u<<(bb+3))) ? 0.f : a3;                                   \
      P0.d[t4&1][(t4>>1)*2]   = cvtpk(a0, a1);                                \
      P0.d[t4&1][(t4>>1)*2+1] = cvtpk(a2, a3);                                \
      float c0 = __builtin_amdgcn_exp2f(st1[t4][0] - mj);                     \
      float c1 = __builtin_amdgcn_exp2f(st1[t4][1] - mj);                     \
      float c2 = __builtin_amdgcn_exp2f(st1[t4][2] - mj);                     \
      float c3 = __builtin_amdgcn_exp2f(st1[t4][3] - mj);                     \
      c0 = (bm1 & (1u<<(bb+0))) ? 0.f : c0;                                   \
      c1 = (bm1 & (1u<<(bb+1))) ? 0.f : c1;                                   \
      c2 = (bm1 & (1u<<(bb+2))) ? 0.f : c2;                                   \
      c3 = (bm1 & (1u<<(bb+3))) ? 0.f : c3;                                   \
      P1.d[t4&1][(t4>>1)*2]   = cvtpk(c0, c1);                                \
      P1.d[t4&1][(t4>>1)*2+1] = cvtpk(c2, c3);                                \
    }                                                                         \
    __builtin_amdgcn_s_setprio(1);                                            \
    _Pragma("unroll")                                                         \
    for (int kk=0;kk<2;kk++) {                                                \
      lj40 = __builtin_amdgcn_mfma_f32_16x16x32_bf16(P0.v[kk], vones, lj40, 0,0,0); \
      lj41 = __builtin_amdgcn_mfma_f32_16x16x32_bf16(P1.v[kk], vones, lj41, 0,0,0); \
      _Pragma("unroll")                                                       \
      for (int t4=0;t4<4;t4++) {                                              \
        bf16x8 bv8 = *(const bf16x8*)(lds + 16384 + (CUR)*8192 + rdO[t4][kk]); \
        o20[t4] = __builtin_amdgcn_mfma_f32_16x16x32_bf16(P0.v[kk], bv8, o20[t4], 0,0,0); \
        o21[t4] = __builtin_amdgcn_mfma_f32_16x16x32_bf16(P1.v[kk], bv8, o21[t4], 0,0,0); \
      }                                                                       \
    }                                                                         \
    __builtin_amdgcn_s_setprio(0);                                            \
    float pm0 = fmaxf(fmaxf(fmaxf(st0[0][0],st0[0][1]),fmaxf(st0[0][2],st0[0][3])),  \
                fmaxf(fmaxf(fmaxf(st0[1][0],st0[1][1]),fmaxf(st0[1][2],st0[1][3])),  \
                fmaxf(fmaxf(fmaxf(st0[2][0],st0[2][1]),fmaxf(st0[2][2],st0[2][3])),  \
                      fmaxf(fmaxf(st0[3][0],st0[3][1]),fmaxf(st0[3][2],st0[3][3]))))); \
    float pm1 = fmaxf(fmaxf(fmaxf(st1[0][0],st1[0][1]),fmaxf(st1[0][2],st1[0][3])),  \
                fmaxf(fmaxf(fmaxf(st1[1][0],st1[1][1]),fmaxf(st1[1][2],st1[1][3])),  \
                fmaxf(fmaxf(fmaxf(st1[2][0],st1[2][1]),fmaxf(st1[2][2],st1[2][3])),  \
                      fmaxf(fmaxf(st1[3][0],st1[3][1]),fmaxf(st1[3][2],st1[3][3]))))); \
    float pm = fmaxf(pm0, pm1);                                               \
    if (__any(pm > mj + 7.f)) {                                               \
      pm = fmaxf(pm, __shfl_xor(pm, 16));                                     \
      pm = fmaxf(pm, __shfl_xor(pm, 32));                                     \
      float mn = fmaxf(mj, pm);                                               \
      float alpha = __builtin_amdgcn_exp2f(mj - mn);                          \
      mj = mn;                                                                \
      _Pragma("unroll")                                                       \
      for (int j=0;j<4;j++) {                                                 \
        float aj = __shfl(alpha, 4*g + j);                                    \
        lj40[j] *= aj; lj41[j] *= aj;                                         \
        _Pragma("unroll")                                                     \
        for (int t4=0;t4<4;t4++) { o20[t4][j] *= aj; o21[t4][j] *= aj; }      \
      }                                                                       \
    } }

__global__ __launch_bounds__(256,2) void fattn(const unsigned short* __restrict__ Qp,
                                               const unsigned short* __restrict__ Kp,
                                               const unsigned short* __restrict__ Vt,
                                               const unsigned long long* __restrict__ bits,
                                               unsigned short* __restrict__ attO) {
  // layout: [K buf0 8K][K buf1 8K][V buf0 8K][V buf1 8K]
  __shared__ __align__(16) char lds[32768];
  const int tid = threadIdx.x, lane = tid & 63, wid = tid >> 6;
  const int g = lane >> 4, cc = lane & 15;
  const int g8 = g << 3;

  // XCD-aware decode: 512 blocks; xcd = n&7 owns 2 bh x 32 q-blocks (L2-resident KV)
  const int n = blockIdx.x;
  const int xcd = n & 7, idx = n >> 3;
  const int bh = xcd*2 + (idx >> 5);
  const int qb = idx & 31;
  const int b = bh >> 3;
  const int q0w = qb*128 + wid*32;

  const unsigned short* Qb = Qp + (size_t)bh*S_*HD_;
  const unsigned short* Kb = Kp + (size_t)bh*S_*HD_;
  const unsigned short* Vb = Vt + (size_t)bh*HD_*S_;   // [hd][s]

  // Q as 2 B-frags (32 q-rows), pre-scaled by QSCALE
  bf16x8 aq00 = *(const bf16x8*)(Qb + (size_t)(q0w+cc)*HD_ + g8);
  bf16x8 aq01 = *(const bf16x8*)(Qb + (size_t)(q0w+cc)*HD_ + 32 + g8);
  bf16x8 aq10 = *(const bf16x8*)(Qb + (size_t)(q0w+16+cc)*HD_ + g8);
  bf16x8 aq11 = *(const bf16x8*)(Qb + (size_t)(q0w+16+cc)*HD_ + 32 + g8);

  // loop-invariant swizzled LDS read offsets (same pattern for K and V tiles)
  int rdO[4][2];
  #pragma unroll
  for (int t4=0;t4<4;t4++) {
    int row = t4*16 + cc;
    int base = row*128 + ((g ^ (row&7)) << 4);
    rdO[t4][0] = base;
    rdO[t4][1] = base ^ 64;
  }

  // DMA source addresses (swizzle+perm folded into per-lane global source)
  const int p0 = wid*8 + (lane >> 3);
  const int sl = lane & 7;
  const int cK = sl ^ (p0 & 7);
  const unsigned short* gkA = Kb + (size_t)kperm_inv(p0)      *HD_ + cK*8;
  const unsigned short* gkB = Kb + (size_t)kperm_inv(p0 + 32) *HD_ + cK*8;
  const unsigned short* gvA = Vb + (size_t)p0*S_ + cK*8;
  const unsigned short* gvB = gvA + (size_t)32*S_;
  const int woff = wid*1024;

  // mask-bit pointers (one u64 per tile per q-row)
  const unsigned long long* mb0p = bits + ((size_t)(b*S_ + q0w +      cc)) * (S_/64);
  const unsigned long long* mb1p = bits + ((size_t)(b*S_ + q0w + 16 + cc)) * (S_/64);

  union { unsigned d[4]; bf16x8 v; } onesu;
  onesu.d[0] = onesu.d[1] = onesu.d[2] = onesu.d[3] = 0x3F803F80u;
  const bf16x8 vones = onesu.v;

  f32x4 o20[4], o21[4];
  #pragma unroll
  for (int t4=0;t4<4;t4++) { o20[t4] = (f32x4){0.f,0.f,0.f,0.f}; o21[t4] = (f32x4){0.f,0.f,0.f,0.f}; }
  f32x4 lj40 = (f32x4){0.f,0.f,0.f,0.f};
  f32x4 lj41 = (f32x4){0.f,0.f,0.f,0.f};
  float mj = 0.f;     // stale running max (log2 domain); scores O(1) so 0 is safe

  unsigned long long mA0=0, mA1=0, mB0=0, mB1=0;

  const int NT = S_/64;   // 64

  // prologue: stage tile 0 into buf0, bits(0) into mA
  FA_ISSUE(0, mA0, mA1)

  #pragma unroll 1
  for (int t2 = 0; t2 < NT; t2 += 2) {
    FA_TILE(0, mA0, mA1, true,         mB0, mB1)
    FA_TILE(1, mB0, mB1, (t2+2 < NT),  mA0, mA1)
  }

  // epilogue: inv from lj4 directly (already in o-fragment layout)
  const int h = bh & (H_-1);
  #pragma unroll
  for (int j=0;j<4;j++) {
    float i0 = __builtin_amdgcn_rcpf(lj40[j]);
    float i1 = __builtin_amdgcn_rcpf(lj41[j]);
    int qr0 = q0w + 4*g + j;
    int qr1 = q0w + 16 + 4*g + j;
    unsigned short* orow0 = attO + ((size_t)b*S_ + qr0)*D_ + h*HD_;
    unsigned short* orow1 = attO + ((size_t)b*S_ + qr1)*D_ + h*HD_;
    #pragma unroll
    for (int t4=0;t4<4;t4++) {
      orow0[t4*16 + cc] = f2bf(o20[t4][j] * i0);
      orow1[t4*16 + cc] = f2bf(o21[t4][j] * i1);
    }
  }
}

extern "C" void kernel_launch(void* const* d_in, const int* in_sizes, int n_in,
                              void* d_out, int out_size, void* d_ws, size_t ws_size,
                              hipStream_t stream) {
  const float* q    = (const float*)d_in[0];
  const float* k    = (const float*)d_in[1];
  const float* v    = (const float*)d_in[2];
  const int*   mask = (const int*)  d_in[3];
  const float* wq   = (const float*)d_in[4];
  const float* bq   = (const float*)d_in[5];
  const float* wk   = (const float*)d_in[6];
  const float* bk   = (const float*)d_in[7];
  const float* wv   = (const float*)d_in[8];
  const float* bv   = (const float*)d_in[9];
  const float* wo   = (const float*)d_in[10];
  const float* bo   = (const float*)d_in[11];

  char* ws = (char*)d_ws;
  const size_t SZ_MAT = (size_t)M_ * D_ * 2;   // 8 MiB bf16 [8192,512]
  const size_t SZ_W   = (size_t)D_ * D_ * 2;   // 512 KiB
  unsigned short* wqt = (unsigned short*)(ws);
  unsigned short* wkt = (unsigned short*)(ws + SZ_W);
  unsigned short* wvt = (unsigned short*)(ws + 2*SZ_W);
  unsigned short* wot = (unsigned short*)(ws + 3*SZ_W);
  unsigned short* Qp  = (unsigned short*)(ws + 4*SZ_W);
  unsigned short* Kp  = (unsigned short*)(ws + 4*SZ_W + SZ_MAT);
  unsigned short* Vt  = (unsigned short*)(ws + 4*SZ_W + 2*SZ_MAT);
  unsigned short* att = (unsigned short*)(ws + 4*SZ_W + 3*SZ_MAT);
  unsigned long long* bits = (unsigned long long*)(ws + 4*SZ_W + 4*SZ_MAT);  // 4 MiB

  mpack<<<2048, 256, 0, stream>>>(mask, bits);
  wtrans4<<<dim3(16,16,4), 256, 0, stream>>>(wq, wk, wv, wo, wqt, wkt, wvt, wot);
  qkv_gemm<<<dim3(64,4,3), 256, 0, stream>>>(q, k, v, wqt, wkt, wvt,
                                             bq, bk, bv, Qp, Kp, Vt);
  fattn<<<512, 256, 0, stream>>>(Qp, Kp, Vt, bits, att);
  o_gemm<<<dim3(64,4), 256, 0, stream>>>(att, wot, bo, (float*)d_out);
}

// Round 7
// 189.317 us; speedup vs baseline: 1.3598x; 1.0704x over previous
//
#include <hip/hip_runtime.h>
#include <stdint.h>

#define B_ 2
#define S_ 4096
#define D_ 512
#define H_ 8
#define HD_ 64
#define M_ (B_*S_)   // 8192

typedef __attribute__((ext_vector_type(8))) short bf16x8;
typedef __attribute__((ext_vector_type(4))) float f32x4;

#define QSCALE (0.125f * 1.44269504088896341f)  // 1/sqrt(64) * log2(e)
#define MFMA16(A,B,C) __builtin_amdgcn_mfma_f32_16x16x32_bf16((A),(B),(C),0,0,0)

__device__ __forceinline__ unsigned short f2bf(float f) {
  union { float f; unsigned u; } un; un.f = f;
  unsigned u = un.u;
  return (unsigned short)((u + 0x7fffu + ((u >> 16) & 1u)) >> 16);
}

__device__ __forceinline__ unsigned cvtpk(float lo, float hi) {
  unsigned r;
  asm("v_cvt_pk_bf16_f32 %0, %1, %2" : "=v"(r) : "v"(lo), "v"(hi));
  return r;
}

// async 16B global -> LDS (linear dest: wave-uniform base + lane*16)
__device__ __forceinline__ void gl16(const void* g, void* l) {
  __builtin_amdgcn_global_load_lds(
      (const __attribute__((address_space(1))) void*)g,
      (__attribute__((address_space(3))) void*)l, 16, 0, 0);
}

// K-row permutation: lK row p holds K[kperm_inv(p)].
__device__ __forceinline__ int kperm_inv(int p) {
  return ((p & 0x1C) << 1) | ((p & 0x20) >> 3) | (p & 3);
}

// ---------------- mask bit-pack: int32 [2,S,S] -> 1 bit per elem -------------
__global__ __launch_bounds__(256) void mpack(const int* __restrict__ mask,
                                             unsigned long long* __restrict__ bits) {
  const int nw = (gridDim.x * 256) >> 6;
  int w = (blockIdx.x * 256 + threadIdx.x) >> 6;
  int lane = threadIdx.x & 63;
  const int NWORD = (int)((size_t)B_ * S_ * S_ / 64);
  for (int word = w; word < NWORD; word += nw) {
    int m = mask[(size_t)word * 64 + lane];
    unsigned long long bal = __ballot(m != 0);
    if (lane == 0) bits[word] = bal;
  }
}

// ---------------- weight transpose: W[K][N] f32 -> Wt[N][K] bf16 ----------------
__global__ __launch_bounds__(256) void wtrans4(const float* __restrict__ w0, const float* __restrict__ w1,
                                               const float* __restrict__ w2, const float* __restrict__ w3,
                                               unsigned short* __restrict__ t0, unsigned short* __restrict__ t1,
                                               unsigned short* __restrict__ t2, unsigned short* __restrict__ t3) {
  const float* W = blockIdx.z==0?w0: blockIdx.z==1?w1: blockIdx.z==2?w2:w3;
  unsigned short* T = blockIdx.z==0?t0: blockIdx.z==1?t1: blockIdx.z==2?t2:t3;
  __shared__ float tile[32][33];
  int n0 = blockIdx.x*32, k0 = blockIdx.y*32;
  int tx = threadIdx.x & 31, ty = threadIdx.x >> 5;
  #pragma unroll
  for (int i=0;i<4;i++)
    tile[ty + i*8][tx] = W[(size_t)(k0 + ty + i*8)*D_ + n0 + tx];
  __syncthreads();
  #pragma unroll
  for (int i=0;i<4;i++)
    T[(size_t)(n0 + ty + i*8)*D_ + k0 + tx] = f2bf(tile[tx][ty + i*8]);
}

// ---------------- 128x128 bf16 MFMA GEMM, BK=64, 4 waves (2x2), XOR-swizzled LDS ----
template<int OUT_MODE, int CONVA>
__device__ __forceinline__ void gemm_body(const void* __restrict__ Ap,
                                          const unsigned short* __restrict__ Wt,
                                          const float* __restrict__ bias,
                                          void* __restrict__ Out, float oscale) {
  __shared__ __align__(16) unsigned short lAB[2*128*64];
  unsigned short* lA = lAB;
  unsigned short* lB = lAB + 128*64;
  int bm = blockIdx.x, bn = blockIdx.y;
  int tid = threadIdx.x, lane = tid & 63, wid = tid >> 6;
  int g = lane >> 4, cc = lane & 15;
  int wm = wid >> 1, wn = wid & 1;

  f32x4 acc[4][4];
  #pragma unroll
  for (int mi=0;mi<4;mi++)
    #pragma unroll
    for (int ni=0;ni<4;ni++)
      acc[mi][ni] = (f32x4){0.f,0.f,0.f,0.f};

  for (int ks = 0; ks < D_; ks += 64) {
    __syncthreads();
    #pragma unroll
    for (int c4 = 0; c4 < 4; c4++) {
      int idx = wid*256 + c4*64 + lane;   // 0..1023 = row*8 + ch
      int row = idx >> 3, ch = idx & 7;
      int sw = ch ^ (row & 7);
      bf16x8 va;
      if (CONVA) {
        const float* a32 = (const float*)Ap + (size_t)(bm*128 + row)*D_ + ks + ch*8;
        float4 f0 = *(const float4*)a32;
        float4 f1 = *(const float4*)(a32 + 4);
        union { unsigned d[4]; bf16x8 v; } u;
        u.d[0] = cvtpk(f0.x, f0.y);
        u.d[1] = cvtpk(f0.z, f0.w);
        u.d[2] = cvtpk(f1.x, f1.y);
        u.d[3] = cvtpk(f1.z, f1.w);
        va = u.v;
      } else {
        va = *(const bf16x8*)((const unsigned short*)Ap + (size_t)(bm*128 + row)*D_ + ks + ch*8);
      }
      bf16x8 vb = *(const bf16x8*)(Wt + (size_t)(bn*128 + row)*D_ + ks + ch*8);
      *(bf16x8*)((char*)lA + row*128 + sw*16) = va;
      *(bf16x8*)((char*)lB + row*128 + sw*16) = vb;
    }
    __syncthreads();
    #pragma unroll
    for (int kk = 0; kk < 2; kk++) {
      bf16x8 af[4], bfv[4];
      #pragma unroll
      for (int mi=0;mi<4;mi++) {
        int row = wm*64 + mi*16 + cc;
        af[mi] = *(const bf16x8*)((const char*)lA + row*128 + (((4*kk+g) ^ (row&7))<<4));
      }
      #pragma unroll
      for (int ni=0;ni<4;ni++) {
        int row = wn*64 + ni*16 + cc;
        bfv[ni] = *(const bf16x8*)((const char*)lB + row*128 + (((4*kk+g) ^ (row&7))<<4));
      }
      #pragma unroll
      for (int mi=0;mi<4;mi++)
        #pragma unroll
        for (int ni=0;ni<4;ni++)
          acc[mi][ni] = MFMA16(af[mi], bfv[ni], acc[mi][ni]);
    }
  }

  if (OUT_MODE == 2) {
    __syncthreads();
    char* ldsT = (char*)lAB + wid*8192;   // 8KB per wave
    #pragma unroll
    for (int ni=0;ni<4;ni++) {
      int n_l = ni*16 + cc;
      float bv = bias[bn*128 + wn*64 + n_l];
      #pragma unroll
      for (int mi=0;mi<4;mi++) {
        ushort4 pk;
        pk.x = f2bf(acc[mi][ni][0] + bv);
        pk.y = f2bf(acc[mi][ni][1] + bv);
        pk.z = f2bf(acc[mi][ni][2] + bv);
        pk.w = f2bf(acc[mi][ni][3] + bv);
        *(ushort4*)(ldsT + n_l*128 + ((32*mi + 8*g) ^ ((n_l&7)<<4))) = pk;
      }
    }
    asm volatile("s_waitcnt lgkmcnt(0)" ::: "memory");
    __builtin_amdgcn_sched_barrier(0);
    #pragma unroll
    for (int it=0; it<8; ++it) {
      int task = it*64 + lane;
      int row = task >> 3, ch = task & 7;
      bf16x8 vv = *(const bf16x8*)(ldsT + row*128 + ((ch ^ (row&7))<<4));
      int n_g = bn*128 + wn*64 + row;
      int m_g = bm*128 + wm*64 + ch*8;
      int bb = m_g >> 12, ss = m_g & (S_-1);
      int hh = n_g >> 6, hd = n_g & 63;
      *(bf16x8*)((unsigned short*)Out + (((size_t)(bb*H_+hh)*HD_ + hd)*S_ + ss)) = vv;
    }
    return;
  }

  #pragma unroll
  for (int ni=0;ni<4;ni++) {
    int n = bn*128 + wn*64 + ni*16 + cc;
    float bv = bias[n];
    #pragma unroll
    for (int mi=0;mi<4;mi++) {
      f32x4 vacc = acc[mi][ni];
      #pragma unroll
      for (int j=0;j<4;j++) {
        int r = bm*128 + wm*64 + mi*16 + 4*g + j;
        float val = (vacc[j] + bv) * oscale;
        if (OUT_MODE == 0) {
          int b = r >> 12, s = r & (S_-1);
          int h = n >> 6, hd = n & 63;
          ((unsigned short*)Out)[(((size_t)(b*H_ + h)*S_ + s) << 6) + hd] = f2bf(val);
        } else {
          ((float*)Out)[(size_t)r*D_ + n] = val;
        }
      }
    }
  }
}

__global__ __launch_bounds__(256,3) void qkv_gemm(
    const float* __restrict__ q32, const float* __restrict__ k32, const float* __restrict__ v32,
    const unsigned short* __restrict__ wqt, const unsigned short* __restrict__ wkt,
    const unsigned short* __restrict__ wvt,
    const float* __restrict__ bq, const float* __restrict__ bk, const float* __restrict__ bv,
    unsigned short* __restrict__ Qp, unsigned short* __restrict__ Kp,
    unsigned short* __restrict__ Vt) {
  if (blockIdx.z == 0)      gemm_body<0,1>(q32, wqt, bq, Qp, QSCALE);
  else if (blockIdx.z == 1) gemm_body<0,1>(k32, wkt, bk, Kp, 1.0f);
  else                      gemm_body<2,1>(v32, wvt, bv, Vt, 1.0f);
}

__global__ __launch_bounds__(256,3) void o_gemm(const unsigned short* __restrict__ att,
                                                const unsigned short* __restrict__ wot,
                                                const float* __restrict__ bo,
                                                float* __restrict__ out) {
  gemm_body<1,0>(att, wot, bo, out, 1.0f);
}

// ---------------- flash attention: QBLK=128 (4 waves x 32 q), KVBLK=64 ------------
// Software-pipelined: tile t body = QK(t) MFMA || SM(t-1) VALU -> PV(t-1) MFMA.
// 4-slot LDS ring (64KB), DMA prefetch depth 2, counted vmcnt(6) (never drain to 0).

#define WAITBAR { asm volatile("s_waitcnt vmcnt(6)" ::: "memory"); \
                  __builtin_amdgcn_s_barrier(); }

#define ISSUE(SLOT, TIDX) { \
    int tn_ = (TIDX) < NT ? (TIDX) : NT-1; \
    char* kb_ = lds + (SLOT)*8192 + woff; \
    char* vb_ = lds + 32768 + (SLOT)*8192 + woff; \
    gl16(gkA + (size_t)tn_*(64*HD_), kb_); \
    gl16(gkB + (size_t)tn_*(64*HD_), kb_ + 4096); \
    gl16(gvA + tn_*64, vb_); \
    gl16(gvB + tn_*64, vb_ + 4096); \
    msk0[SLOT] = mb0p[tn_]; \
    msk1[SLOT] = mb1p[tn_]; }

#define QK(SLOT, S0, S1) { \
    __builtin_amdgcn_s_setprio(1); \
    _Pragma("unroll") \
    for (int t4=0;t4<4;t4++) { \
      bf16x8 ak0 = *(const bf16x8*)(lds + (SLOT)*8192 + rdO[t4][0]); \
      bf16x8 ak1 = *(const bf16x8*)(lds + (SLOT)*8192 + rdO[t4][1]); \
      f32x4 s0 = (f32x4){0.f,0.f,0.f,0.f}; \
      s0 = MFMA16(ak0, aq00, s0); \
      s0 = MFMA16(ak1, aq01, s0); \
      f32x4 s1 = (f32x4){0.f,0.f,0.f,0.f}; \
      s1 = MFMA16(ak0, aq10, s1); \
      s1 = MFMA16(ak1, aq11, s1); \
      S0[t4] = s0; S1[t4] = s1; \
    } \
    __builtin_amdgcn_s_setprio(0); }

#define SMPV(S0, S1, VSLOT, MSLOT) { \
    unsigned long long sh0 = msk0[MSLOT] >> g8, sh1 = msk1[MSLOT] >> g8; \
    unsigned lo0=(unsigned)sh0, hi0=(unsigned)(sh0>>32); \
    unsigned lo1=(unsigned)sh1, hi1=(unsigned)(sh1>>32); \
    union { unsigned d[2][4]; bf16x8 v[2]; } P0_, P1_; \
    _Pragma("unroll") \
    for (int t4=0;t4<4;t4++) { \
      unsigned bm0=(t4&1)?hi0:lo0, bm1=(t4&1)?hi1:lo1; \
      const int bb=(t4>>1)*4; \
      float a0=__builtin_amdgcn_exp2f(S0[t4][0]-mj); \
      float a1=__builtin_amdgcn_exp2f(S0[t4][1]-mj); \
      float a2=__builtin_amdgcn_exp2f(S0[t4][2]-mj); \
      float a3=__builtin_amdgcn_exp2f(S0[t4][3]-mj); \
      a0=(bm0&(1u<<(bb+0)))?0.f:a0; a1=(bm0&(1u<<(bb+1)))?0.f:a1; \
      a2=(bm0&(1u<<(bb+2)))?0.f:a2; a3=(bm0&(1u<<(bb+3)))?0.f:a3; \
      P0_.d[t4&1][(t4>>1)*2]   = cvtpk(a0,a1); \
      P0_.d[t4&1][(t4>>1)*2+1] = cvtpk(a2,a3); \
      float c0=__builtin_amdgcn_exp2f(S1[t4][0]-mj); \
      float c1=__builtin_amdgcn_exp2f(S1[t4][1]-mj); \
      float c2=__builtin_amdgcn_exp2f(S1[t4][2]-mj); \
      float c3=__builtin_amdgcn_exp2f(S1[t4][3]-mj); \
      c0=(bm1&(1u<<(bb+0)))?0.f:c0; c1=(bm1&(1u<<(bb+1)))?0.f:c1; \
      c2=(bm1&(1u<<(bb+2)))?0.f:c2; c3=(bm1&(1u<<(bb+3)))?0.f:c3; \
      P1_.d[t4&1][(t4>>1)*2]   = cvtpk(c0,c1); \
      P1_.d[t4&1][(t4>>1)*2+1] = cvtpk(c2,c3); \
    } \
    __builtin_amdgcn_s_setprio(1); \
    _Pragma("unroll") \
    for (int kk=0;kk<2;kk++) { \
      lj40 = MFMA16(P0_.v[kk], vones, lj40); \
      lj41 = MFMA16(P1_.v[kk], vones, lj41); \
      _Pragma("unroll") \
      for (int t4=0;t4<4;t4++) { \
        bf16x8 bv8 = *(const bf16x8*)(lds + 32768 + (VSLOT)*8192 + rdO[t4][kk]); \
        o20[t4] = MFMA16(P0_.v[kk], bv8, o20[t4]); \
        o21[t4] = MFMA16(P1_.v[kk], bv8, o21[t4]); \
      } \
    } \
    __builtin_amdgcn_s_setprio(0); \
    float pm0 = fmaxf(fmaxf(fmaxf(S0[0][0],S0[0][1]),fmaxf(S0[0][2],S0[0][3])),  \
                fmaxf(fmaxf(fmaxf(S0[1][0],S0[1][1]),fmaxf(S0[1][2],S0[1][3])),  \
                fmaxf(fmaxf(fmaxf(S0[2][0],S0[2][1]),fmaxf(S0[2][2],S0[2][3])),  \
                      fmaxf(fmaxf(S0[3][0],S0[3][1]),fmaxf(S0[3][2],S0[3][3]))))); \
    float pm1 = fmaxf(fmaxf(fmaxf(S1[0][0],S1[0][1]),fmaxf(S1[0][2],S1[0][3])),  \
                fmaxf(fmaxf(fmaxf(S1[1][0],S1[1][1]),fmaxf(S1[1][2],S1[1][3])),  \
                fmaxf(fmaxf(fmaxf(S1[2][0],S1[2][1]),fmaxf(S1[2][2],S1[2][3])),  \
                      fmaxf(fmaxf(S1[3][0],S1[3][1]),fmaxf(S1[3][2],S1[3][3]))))); \
    float pm = fmaxf(pm0, pm1); \
    if (__any(pm > mj + 7.f)) { \
      pm = fmaxf(pm, __shfl_xor(pm, 16)); \
      pm = fmaxf(pm, __shfl_xor(pm, 32)); \
      float mn = fmaxf(mj, pm); \
      float alpha = __builtin_amdgcn_exp2f(mj - mn); \
      mj = mn; \
      _Pragma("unroll") \
      for (int j=0;j<4;j++) { \
        float aj = __shfl(alpha, 4*g + j); \
        lj40[j] *= aj; lj41[j] *= aj; \
        _Pragma("unroll") \
        for (int t4=0;t4<4;t4++) { o20[t4][j] *= aj; o21[t4][j] *= aj; } \
      } \
    } }

__global__ __launch_bounds__(256,2) void fattn(const unsigned short* __restrict__ Qp,
                                               const unsigned short* __restrict__ Kp,
                                               const unsigned short* __restrict__ Vt,
                                               const unsigned long long* __restrict__ bits,
                                               unsigned short* __restrict__ attO) {
  // LDS: K slots 0..32KB (4 x 8KB ring), V slots 32..64KB (4 x 8KB ring)
  __shared__ __align__(16) char lds[65536];
  const int tid = threadIdx.x, lane = tid & 63, wid = tid >> 6;
  const int g = lane >> 4, cc = lane & 15;
  const int g8 = g << 3;

  // XCD-aware decode: 512 blocks; xcd = n&7 owns 2 bh x 32 q-blocks (L2-resident KV)
  const int n = blockIdx.x;
  const int xcd = n & 7, idx = n >> 3;
  const int bh = xcd*2 + (idx >> 5);
  const int qb = idx & 31;
  const int b = bh >> 3;
  const int q0w = qb*128 + wid*32;

  const unsigned short* Qb = Qp + (size_t)bh*S_*HD_;
  const unsigned short* Kb = Kp + (size_t)bh*S_*HD_;
  const unsigned short* Vb = Vt + (size_t)bh*HD_*S_;   // [hd][s]

  // Q as 2 B-frags (32 q-rows), pre-scaled by QSCALE
  bf16x8 aq00 = *(const bf16x8*)(Qb + (size_t)(q0w+cc)*HD_ + g8);
  bf16x8 aq01 = *(const bf16x8*)(Qb + (size_t)(q0w+cc)*HD_ + 32 + g8);
  bf16x8 aq10 = *(const bf16x8*)(Qb + (size_t)(q0w+16+cc)*HD_ + g8);
  bf16x8 aq11 = *(const bf16x8*)(Qb + (size_t)(q0w+16+cc)*HD_ + 32 + g8);

  // loop-invariant swizzled LDS read offsets (same pattern for K and V tiles)
  int rdO[4][2];
  #pragma unroll
  for (int t4=0;t4<4;t4++) {
    int row = t4*16 + cc;
    int base = row*128 + ((g ^ (row&7)) << 4);
    rdO[t4][0] = base;
    rdO[t4][1] = base ^ 64;
  }

  // DMA source addresses (swizzle+perm folded into per-lane global source)
  const int p0 = wid*8 + (lane >> 3);
  const int sl = lane & 7;
  const int cK = sl ^ (p0 & 7);
  const unsigned short* gkA = Kb + (size_t)kperm_inv(p0)      *HD_ + cK*8;
  const unsigned short* gkB = Kb + (size_t)kperm_inv(p0 + 32) *HD_ + cK*8;
  const unsigned short* gvA = Vb + (size_t)p0*S_ + cK*8;
  const unsigned short* gvB = gvA + (size_t)32*S_;
  const int woff = wid*1024;

  // mask-bit row bases (word index = kv-tile)
  const unsigned long long* mb0p = bits + ((size_t)(b*S_ + q0w +      cc)) * (S_/64);
  const unsigned long long* mb1p = bits + ((size_t)(b*S_ + q0w + 16 + cc)) * (S_/64);

  union { unsigned d[4]; bf16x8 v; } onesu;
  onesu.d[0] = onesu.d[1] = onesu.d[2] = onesu.d[3] = 0x3F803F80u;
  const bf16x8 vones = onesu.v;

  f32x4 o20[4], o21[4];
  #pragma unroll
  for (int t4=0;t4<4;t4++) { o20[t4] = (f32x4){0.f,0.f,0.f,0.f}; o21[t4] = (f32x4){0.f,0.f,0.f,0.f}; }
  f32x4 lj40 = (f32x4){0.f,0.f,0.f,0.f};
  f32x4 lj41 = (f32x4){0.f,0.f,0.f,0.f};
  float mj = 0.f;     // stale running max (log2 domain)

  unsigned long long msk0[4], msk1[4];
  f32x4 stA0[4], stA1[4], stB0[4], stB1[4];

  const int NT = S_/64;   // 64

  // prologue: DMA tiles 0,1 into slots 0,1
  ISSUE(0, 0)
  ISSUE(1, 1)

  // peel tiles 0..3 (pipeline fill)
  WAITBAR ISSUE(2, 2) QK(0, stA0, stA1)
  WAITBAR ISSUE(3, 3) QK(1, stB0, stB1) SMPV(stA0, stA1, 0, 0)
  WAITBAR ISSUE(0, 4) QK(2, stA0, stA1) SMPV(stB0, stB1, 1, 1)
  WAITBAR ISSUE(1, 5) QK(3, stB0, stB1) SMPV(stA0, stA1, 2, 2)

  #pragma unroll 1
  for (int t = 4; t < NT; t += 4) {
    WAITBAR ISSUE(2, t+2) QK(0, stA0, stA1) SMPV(stB0, stB1, 3, 3)
    WAITBAR ISSUE(3, t+3) QK(1, stB0, stB1) SMPV(stA0, stA1, 0, 0)
    WAITBAR ISSUE(0, t+4) QK(2, stA0, stA1) SMPV(stB0, stB1, 1, 1)
    WAITBAR ISSUE(1, t+5) QK(3, stB0, stB1) SMPV(stA0, stA1, 2, 2)
  }

  // pipeline drain: SM+PV for tile 63 (st in B, V slot 3, mask set 3)
  SMPV(stB0, stB1, 3, 3)

  // epilogue: inv from lj4 directly (already in o-fragment layout)
  const int h = bh & (H_-1);
  #pragma unroll
  for (int j=0;j<4;j++) {
    float i0 = __builtin_amdgcn_rcpf(lj40[j]);
    float i1 = __builtin_amdgcn_rcpf(lj41[j]);
    int qr0 = q0w + 4*g + j;
    int qr1 = q0w + 16 + 4*g + j;
    unsigned short* orow0 = attO + ((size_t)b*S_ + qr0)*D_ + h*HD_;
    unsigned short* orow1 = attO + ((size_t)b*S_ + qr1)*D_ + h*HD_;
    #pragma unroll
    for (int t4=0;t4<4;t4++) {
      orow0[t4*16 + cc] = f2bf(o20[t4][j] * i0);
      orow1[t4*16 + cc] = f2bf(o21[t4][j] * i1);
    }
  }
}

extern "C" void kernel_launch(void* const* d_in, const int* in_sizes, int n_in,
                              void* d_out, int out_size, void* d_ws, size_t ws_size,
                              hipStream_t stream) {
  const float* q    = (const float*)d_in[0];
  const float* k    = (const float*)d_in[1];
  const float* v    = (const float*)d_in[2];
  const int*   mask = (const int*)  d_in[3];
  const float* wq   = (const float*)d_in[4];
  const float* bq   = (const float*)d_in[5];
  const float* wk   = (const float*)d_in[6];
  const float* bk   = (const float*)d_in[7];
  const float* wv   = (const float*)d_in[8];
  const float* bv   = (const float*)d_in[9];
  const float* wo   = (const float*)d_in[10];
  const float* bo   = (const float*)d_in[11];

  char* ws = (char*)d_ws;
  const size_t SZ_MAT = (size_t)M_ * D_ * 2;   // 8 MiB bf16 [8192,512]
  const size_t SZ_W   = (size_t)D_ * D_ * 2;   // 512 KiB
  unsigned short* wqt = (unsigned short*)(ws);
  unsigned short* wkt = (unsigned short*)(ws + SZ_W);
  unsigned short* wvt = (unsigned short*)(ws + 2*SZ_W);
  unsigned short* wot = (unsigned short*)(ws + 3*SZ_W);
  unsigned short* Qp  = (unsigned short*)(ws + 4*SZ_W);
  unsigned short* Kp  = (unsigned short*)(ws + 4*SZ_W + SZ_MAT);
  unsigned short* Vt  = (unsigned short*)(ws + 4*SZ_W + 2*SZ_MAT);
  unsigned short* att = (unsigned short*)(ws + 4*SZ_W + 3*SZ_MAT);
  unsigned long long* bits = (unsigned long long*)(ws + 4*SZ_W + 4*SZ_MAT);  // 4 MiB

  mpack<<<2048, 256, 0, stream>>>(mask, bits);
  wtrans4<<<dim3(16,16,4), 256, 0, stream>>>(wq, wk, wv, wo, wqt, wkt, wvt, wot);
  qkv_gemm<<<dim3(64,4,3), 256, 0, stream>>>(q, k, v, wqt, wkt, wvt,
                                             bq, bk, bv, Qp, Kp, Vt);
  fattn<<<512, 256, 0, stream>>>(Qp, Kp, Vt, bits, att);
  o_gemm<<<dim3(64,4), 256, 0, stream>>>(att, wot, bo, (float*)d_out);
}